// Round 6
// baseline (781.584 us; speedup 1.0000x reference)
//
#include <hip/hip_runtime.h>

// Model dims (fixed by the problem)
#define TT    128
#define CC    64
#define HH    4
#define SS    16
#define D4    256     // 4*C
#define HID_  256
#define VV    32000
#define NPE_  4
#define RR    256     // B*T
#define NBLK  256     // persistent-kernel grid (1 block per row)
#define LOG2E 1.44269504f
#define BAR_STRIDE 1024   // words per barrier slot

__device__ __forceinline__ float wred_sum(float v) {
#pragma unroll
    for (int off = 32; off; off >>= 1) v += __shfl_xor(v, off, 64);
    return v;
}
__device__ __forceinline__ float wred_max(float v) {
#pragma unroll
    for (int off = 32; off; off >>= 1) v = fmaxf(v, __shfl_xor(v, off, 64));
    return v;
}
// sigmoid via exp2 + v_rcp (fast, ~1ulp)
__device__ __forceinline__ float sigm(float x) {
    return __builtin_amdgcn_rcpf(1.f + exp2f(-x * LOG2E));
}
// pre-scaled input (already * log2e)
__device__ __forceinline__ float sigm2(float t) {
    return __builtin_amdgcn_rcpf(1.f + exp2f(-t));
}

// ---- two-level tree grid barrier: 16 groups x 16 blocks ----
// layout per slot (words): grpCnt[g]@g*16, glbCnt@256, go[g]@320+g*16
__device__ __forceinline__ void gbar(unsigned* bar, int slot) {
    __syncthreads();
    if (threadIdx.x == 0) {
        unsigned* base = bar + slot * BAR_STRIDE;
        int g = (int)(blockIdx.x >> 4);
        unsigned old = __hip_atomic_fetch_add(base + g * 16, 1u,
                          __ATOMIC_ACQ_REL, __HIP_MEMORY_SCOPE_AGENT);
        if (old == 15u) {
            unsigned o2 = __hip_atomic_fetch_add(base + 256, 1u,
                          __ATOMIC_ACQ_REL, __HIP_MEMORY_SCOPE_AGENT);
            if (o2 == 15u) {
#pragma unroll
                for (int gg = 0; gg < 16; ++gg)
                    __hip_atomic_store(base + 320 + gg * 16, 1u,
                          __ATOMIC_RELEASE, __HIP_MEMORY_SCOPE_AGENT);
            }
        }
        // relaxed poll (no cache-maintenance per iteration), acquire once
        while (__hip_atomic_load(base + 320 + g * 16, __ATOMIC_RELAXED,
                                 __HIP_MEMORY_SCOPE_AGENT) == 0u)
            __builtin_amdgcn_s_sleep(1);
        (void)__hip_atomic_load(base + 320 + g * 16, __ATOMIC_ACQUIRE,
                                __HIP_MEMORY_SCOPE_AGENT);
    }
    __syncthreads();
}

// =================== persistent body kernel ===================
// A-phase: block = (h, kq, 8-row tile); B-phase: block = row
__global__ void __launch_bounds__(256, 2) k_body(
    const int* __restrict__ idx, const float* __restrict__ tok,
    const float* __restrict__ pe_tab, const float* __restrict__ peW1,
    const float* __restrict__ peb1, const float* __restrict__ peW2,
    const float* __restrict__ peb2, const float* __restrict__ peg,
    const float* __restrict__ pebb,
    const float* __restrict__ ln1g, const float* __restrict__ ln1b,
    const float* __restrict__ attW1, const float* __restrict__ ab1,
    const float* __restrict__ aw2, const float* __restrict__ ab2,
    const float* __restrict__ valW,
    const float* __restrict__ projW, const float* __restrict__ projb,
    const float* __restrict__ g2, const float* __restrict__ b2,
    const float* __restrict__ fW1, const float* __restrict__ fb1,
    const float* __restrict__ fW2, const float* __restrict__ fb2,
    const float* __restrict__ g3, const float* __restrict__ b3,
    float* __restrict__ x, float* __restrict__ v,
    float* __restrict__ Kp, float* __restrict__ Qp, unsigned* __restrict__ bar) {

    const int b = blockIdx.x, tid = threadIdx.x;
    const int lane = tid & 63, wv = tid >> 6;
    // A mapping
    const int rg = b & 31, kq = (b >> 5) & 1, h = b >> 6;
    const int r0 = rg * 8;
    // B mapping
    const int row = b, bat = row >> 7, i = row & 127;

    __shared__ float x1[8][128];                     // A: [pos | xn]
    __shared__ float s_pe[8][CC], s_h1[8][CC];       // A: pe FFN temporaries
    __shared__ __align__(16) float q_s[HH][D4];      // B
    __shared__ __align__(16) float w2_s[HH][D4];
    __shared__ float sc[HH][TT];
    __shared__ float part[HH][4][SS];
    __shared__ float o_s[CC], s_x[CC], s_h[HID_], red[4][CC];

    // w2 (constant across p): fold C^-0.5
    for (int e = tid; e < HH * D4; e += 256)
        w2_s[e >> 8][e & 255] = aw2[e] * 0.125f;

    for (int p = 0; p < NPE_; ++p) {
        // ================= phase A =================
        {
            const float* pW1 = peW1 + p * CC * CC;
            const float* pW2 = peW2 + p * CC * CC;
            // each wave: rows wv and wv+4 — pos FFN + LN, then LN1(x)
#pragma unroll
            for (int pass = 0; pass < 2; ++pass) {
                int rr = wv + pass * 4;
                int r = r0 + rr, t = r & (TT - 1);
                s_pe[rr][lane] = pe_tab[(p * TT + t) * CC + lane];
                float a = peb1[p * CC + lane];
                for (int k = 0; k < CC; k++) a += s_pe[rr][k] * pW1[k * CC + lane];
                s_h1[rr][lane] = sigm(a);
                float a2 = peb2[p * CC + lane];
                for (int k = 0; k < CC; k++) a2 += s_h1[rr][k] * pW2[k * CC + lane];
                float m = wred_sum(a2) * (1.f / CC);
                float d = a2 - m;
                float var = wred_sum(d * d) * (1.f / CC);
                x1[rr][lane] = d * rsqrtf(var + 1e-5f) * peg[p * CC + lane]
                             + pebb[p * CC + lane];
                // LN1 half
                float xv = (p == 0) ? tok[idx[r] * CC + lane] : x[r * CC + lane];
                if (p == 0 && kq == 0 && h == 0) x[r * CC + lane] = xv;  // embed
                m = wred_sum(xv) * (1.f / CC);
                d = xv - m;
                var = wred_sum(d * d) * (1.f / CC);
                x1[rr][64 + lane] = d * rsqrtf(var + 1e-5f) * ln1g[lane] + ln1b[lane];
            }
            __syncthreads();
            // K/Q tile GEMM: 8 rows x 256 cols, k=128
            const float* w = attW1 + (h * D4 + kq * 128) * D4;
            float acc[8] = {0, 0, 0, 0, 0, 0, 0, 0};
            for (int c = 0; c < 128; c++) {
                float wvv = w[c * D4 + tid];
#pragma unroll
                for (int rr = 0; rr < 8; rr++) acc[rr] += x1[rr][c] * wvv;
            }
            float badd = kq ? 0.f : ab1[h * D4 + tid];   // fold b1 into K
            float* outKQ = kq ? Qp : Kp;
#pragma unroll
            for (int rr = 0; rr < 8; rr++)               // pre-scale by log2e
                outKQ[(h * RR + r0 + rr) * D4 + tid] = (acc[rr] + badd) * LOG2E;
            // V projection (kq==0 blocks): 8 rows x 16 s for head h
            if (kq == 0 && tid < 128) {
                int rr = tid >> 4, s = tid & 15;
                const float* wvw = valW + h * CC * SS;
                float a = 0.f;
                for (int k = 0; k < CC; k++) a += x1[rr][64 + k] * wvw[k * SS + s];
                v[(h * RR + r0 + rr) * SS + s] = a;
            }
        }
        gbar(bar, 2 * p);
        // ================= phase B (row = b) =================
        {
            const int hB = wv;
            for (int e = tid; e < HH * D4; e += 256)
                q_s[e >> 8][e & 255] = Qp[((e >> 8) * RR + row) * D4 + (e & 255)];
            __syncthreads();
            // scores: lane = j (two j's), d-serial, both passes share q/w reads
            const float* Kb = Kp + (hB * RR + bat * TT) * D4;
            float b2s = ab2[hB] * 0.125f;
            int j0 = lane, j1 = lane + 64;
            bool do0 = (j0 <= i), do1 = (j1 <= i);
            const float* kj0 = Kb + j0 * D4;
            const float* kj1 = Kb + j1 * D4;
            float a0 = 0.f, a1 = 0.f;
            for (int d = 0; d < D4; d += 4) {
                float4 q4 = *(const float4*)&q_s[hB][d];
                float4 w4 = *(const float4*)&w2_s[hB][d];
                if (do0) {
                    float4 k0 = *(const float4*)(kj0 + d);
                    a0 += sigm2(q4.x + k0.x) * w4.x + sigm2(q4.y + k0.y) * w4.y +
                          sigm2(q4.z + k0.z) * w4.z + sigm2(q4.w + k0.w) * w4.w;
                }
                if (do1) {
                    float4 k1 = *(const float4*)(kj1 + d);
                    a1 += sigm2(q4.x + k1.x) * w4.x + sigm2(q4.y + k1.y) * w4.y +
                          sigm2(q4.z + k1.z) * w4.z + sigm2(q4.w + k1.w) * w4.w;
                }
            }
            if (do0) sc[hB][j0] = a0 + b2s;
            if (do1) sc[hB][j1] = a1 + b2s;
            // softmax (wave hB handles head hB)
            {
                float s0 = (lane <= i) ? sc[hB][lane] : -1e30f;
                float s1 = (lane + 64 <= i) ? sc[hB][lane + 64] : -1e30f;
                float m = wred_max(fmaxf(s0, s1));
                float e0 = (lane <= i) ? __expf(s0 - m) : 0.f;
                float e1 = (lane + 64 <= i) ? __expf(s1 - m) : 0.f;
                float inv = __builtin_amdgcn_rcpf(wred_sum(e0 + e1));
                sc[hB][lane] = e0 * inv;
                sc[hB][lane + 64] = e1 * inv;
            }
            // PV
            {
                int jg = lane >> 4, s = lane & 15;
                const float* vb = v + (hB * RR + bat * TT) * SS;
                float acc = 0.f;
                for (int j = jg; j <= i; j += 4) acc += sc[hB][j] * vb[j * SS + s];
                part[hB][jg][s] = acc;
            }
            __syncthreads();
            if (tid < CC) {
                int hh = tid >> 4, s = tid & 15;
                o_s[tid] = part[hh][0][s] + part[hh][1][s] + part[hh][2][s] + part[hh][3][s];
            }
            __syncthreads();
            float xv = 0.f;
            if (tid < CC) {
                float acc = projb[tid];
                for (int k = 0; k < CC; k++) acc += o_s[k] * projW[k * CC + tid];
                xv = x[row * CC + tid] + acc;
                float m = wred_sum(xv) * (1.f / CC);
                float d = xv - m;
                float var = wred_sum(d * d) * (1.f / CC);
                s_x[tid] = d * rsqrtf(var + 1e-5f) * g2[tid] + b2[tid];
            }
            __syncthreads();
            {
                float a = fb1[tid];
                for (int k = 0; k < CC; k++) a += s_x[k] * fW1[k * HID_ + tid];
                s_h[tid] = sigm(a);
            }
            __syncthreads();
            {
                int c = tid & 63, q = tid >> 6;
                float acc = 0.f;
                for (int k = q * 64; k < q * 64 + 64; ++k) acc += s_h[k] * fW2[k * CC + c];
                red[q][c] = acc;
            }
            __syncthreads();
            if (tid < CC) {
                float f = fb2[tid] + red[0][tid] + red[1][tid] + red[2][tid] + red[3][tid];
                float x2 = xv + f;
                float m = wred_sum(x2) * (1.f / CC);
                float d = x2 - m;
                float var = wred_sum(d * d) * (1.f / CC);
                x[row * CC + tid] = d * rsqrtf(var + 1e-5f) * g3[tid] + b3[tid];
            }
        }
        if (p < NPE_ - 1) gbar(bar, 2 * p + 1);
        __syncthreads();   // protect x1/s_pe reuse next iteration
    }
}

// =================== lm_head: c-outer register GEMM ===================
// grid (125, 4); block = 256 cols x 64 rows; thread = 2 cols x 32 rows
__global__ void __launch_bounds__(256, 4) k_lmhead(const float* __restrict__ x,
                                                   const float* __restrict__ lmW,
                                                   const float* __restrict__ lmb,
                                                   float* __restrict__ out) {
    int tid = threadIdx.x;
    int cp = tid & 127, rg = tid >> 7;
    int v2 = blockIdx.x * 256 + cp * 2;
    int r0 = blockIdx.y * 64;
    int rbase = rg * 32;
    __shared__ float xT[CC][68];            // transposed x tile, padded
    for (int e = tid; e < 64 * CC; e += 256) {
        int r = e >> 6, c = e & 63;
        xT[c][r] = x[(r0 + r) * CC + c];
    }
    __syncthreads();
    float2 bias = *(const float2*)(lmb + v2);
    float2 acc[32];
#pragma unroll
    for (int rr = 0; rr < 32; rr++) acc[rr] = bias;
    for (int c = 0; c < CC; ++c) {
        float2 w = *(const float2*)(lmW + (size_t)c * VV + v2);
#pragma unroll
        for (int q = 0; q < 8; ++q) {
            float4 xr = *(const float4*)&xT[c][rbase + q * 4];
            acc[q * 4 + 0].x += xr.x * w.x; acc[q * 4 + 0].y += xr.x * w.y;
            acc[q * 4 + 1].x += xr.y * w.x; acc[q * 4 + 1].y += xr.y * w.y;
            acc[q * 4 + 2].x += xr.z * w.x; acc[q * 4 + 2].y += xr.z * w.y;
            acc[q * 4 + 3].x += xr.w * w.x; acc[q * 4 + 3].y += xr.w * w.y;
        }
    }
#pragma unroll
    for (int rr = 0; rr < 32; rr++)
        *(float2*)(out + (size_t)(r0 + rbase + rr) * VV + v2) = acc[rr];
}

extern "C" void kernel_launch(void* const* d_in, const int* in_sizes, int n_in,
                              void* d_out, int out_size, void* d_ws, size_t ws_size,
                              hipStream_t stream) {
    const int*   idx   = (const int*)d_in[0];
    const float* tok   = (const float*)d_in[1];
    const float* petab = (const float*)d_in[2];
    const float* peW1  = (const float*)d_in[3];
    const float* peb1  = (const float*)d_in[4];
    const float* peW2  = (const float*)d_in[5];
    const float* peb2  = (const float*)d_in[6];
    const float* peg   = (const float*)d_in[7];
    const float* pebb  = (const float*)d_in[8];
    const float* ln1g  = (const float*)d_in[9];
    const float* ln1b  = (const float*)d_in[10];
    const float* attW1 = (const float*)d_in[11];
    const float* attb1 = (const float*)d_in[12];
    const float* attW2 = (const float*)d_in[13];
    const float* attb2 = (const float*)d_in[14];
    const float* valW  = (const float*)d_in[15];
    const float* projW = (const float*)d_in[16];
    const float* projb = (const float*)d_in[17];
    const float* ln2g  = (const float*)d_in[18];
    const float* ln2b  = (const float*)d_in[19];
    const float* ffW1  = (const float*)d_in[20];
    const float* ffb1  = (const float*)d_in[21];
    const float* ffW2  = (const float*)d_in[22];
    const float* ffb2  = (const float*)d_in[23];
    const float* ln3g  = (const float*)d_in[24];
    const float* ln3b  = (const float*)d_in[25];
    const float* lmW   = (const float*)d_in[26];
    const float* lmb   = (const float*)d_in[27];

    float* ws  = (float*)d_ws;
    float* x   = ws;                  // 16384
    float* v   = ws + 16384;          // 16384
    float* Kp  = ws + 32768;          // 262144 (pre-scaled, +b1)
    float* Qp  = ws + 294912;         // 262144 (pre-scaled)
    unsigned* bar = (unsigned*)(ws + 600000);   // 7 slots x 4KB

    hipMemsetAsync(bar, 0, 7 * BAR_STRIDE * sizeof(unsigned), stream);
    k_body<<<NBLK, 256, 0, stream>>>(idx, tok, petab, peW1, peb1, peW2, peb2,
                                     peg, pebb, ln1g, ln1b, attW1, attb1, attW2,
                                     attb2, valW, projW, projb, ln2g, ln2b,
                                     ffW1, ffb1, ffW2, ffb2, ln3g, ln3b,
                                     x, v, Kp, Qp, bar);
    k_lmhead<<<dim3(125, 4), 256, 0, stream>>>(x, lmW, lmb, (float*)d_out);
}

// Round 7
// 257.412 us; speedup vs baseline: 3.0363x; 3.0363x over previous
//
#include <hip/hip_runtime.h>

// Model dims (fixed by the problem)
#define TT    128
#define CC    64
#define HH    4
#define SS    16
#define D4    256     // 4*C
#define HID_  256
#define VV    32000
#define NPE_  4
#define RR    256     // B*T
#define LOG2E 1.44269504f

__device__ __forceinline__ float wred_sum(float v) {
#pragma unroll
    for (int off = 32; off; off >>= 1) v += __shfl_xor(v, off, 64);
    return v;
}
__device__ __forceinline__ float wred_max(float v) {
#pragma unroll
    for (int off = 32; off; off >>= 1) v = fmaxf(v, __shfl_xor(v, off, 64));
    return v;
}
__device__ __forceinline__ float sigm(float x) {
    return __builtin_amdgcn_rcpf(1.f + exp2f(-x * LOG2E));
}
__device__ __forceinline__ float sigm2(float t) {   // input pre-scaled by log2e
    return __builtin_amdgcn_rcpf(1.f + exp2f(-t));
}

// ============ embed + all positional embeddings (one launch) ============
// blocks 0..511: pos (p = blk>>7, t = blk&127); blocks 512..767: embed rows
__global__ void k_embed_pos(const int* __restrict__ idx, const float* __restrict__ tok,
                            const float* __restrict__ pe_tab, const float* __restrict__ W1,
                            const float* __restrict__ b1, const float* __restrict__ W2,
                            const float* __restrict__ b2, const float* __restrict__ g,
                            const float* __restrict__ bb,
                            float* __restrict__ x, float* __restrict__ pos) {
    int blk = blockIdx.x, c = threadIdx.x;
    if (blk >= 512) {
        int r = blk - 512;
        x[r * CC + c] = tok[idx[r] * CC + c];
        return;
    }
    int p = blk >> 7, t = blk & 127;
    __shared__ float s_pe[CC], s_h[CC];
    s_pe[c] = pe_tab[(p * TT + t) * CC + c];
    __syncthreads();
    const float* w1 = W1 + p * CC * CC;
    float a = b1[p * CC + c];
    for (int k = 0; k < CC; k++) a += s_pe[k] * w1[k * CC + c];
    s_h[c] = sigm(a);
    __syncthreads();
    const float* w2 = W2 + p * CC * CC;
    float o = b2[p * CC + c];
    for (int k = 0; k < CC; k++) o += s_h[k] * w2[k * CC + c];
    float m = wred_sum(o) * (1.f / CC);
    float d = o - m;
    float var = wred_sum(d * d) * (1.f / CC);
    pos[(p * TT + t) * CC + c] =
        d * rsqrtf(var + 1e-5f) * g[p * CC + c] + bb[p * CC + c];
}

// ============ stage A: LN1 + K/Q proj (+V on kq==0 blocks) ============
// 256 blocks: rg = blk&31 (8 rows), kq = (blk>>5)&1, h = blk>>6
__global__ void __launch_bounds__(256) k_stageA(
    const float* __restrict__ x, const float* __restrict__ pos_p,
    const float* __restrict__ ln1g, const float* __restrict__ ln1b,
    const float* __restrict__ attW1, const float* __restrict__ ab1,
    const float* __restrict__ valW,
    float* __restrict__ Kp, float* __restrict__ Qp, float* __restrict__ v) {
    int blk = blockIdx.x, tid = threadIdx.x;
    int lane = tid & 63, wv = tid >> 6;
    int rg = blk & 31, kq = (blk >> 5) & 1, h = blk >> 6;
    int r0 = rg * 8;
    __shared__ float x1[8][128];
#pragma unroll
    for (int pass = 0; pass < 2; ++pass) {
        int rr = wv + pass * 4;
        float xv = x[(r0 + rr) * CC + lane];
        float m = wred_sum(xv) * (1.f / CC);
        float d = xv - m;
        float var = wred_sum(d * d) * (1.f / CC);
        x1[rr][64 + lane] = d * rsqrtf(var + 1e-5f) * ln1g[lane] + ln1b[lane];
    }
    for (int e = tid; e < 512; e += 256) {
        int rr = e >> 6, cc = e & 63;
        int t = (r0 + rr) & (TT - 1);
        x1[rr][cc] = pos_p[t * CC + cc];
    }
    __syncthreads();
    const float* w = attW1 + (h * D4 + kq * 128) * D4;
    float acc[8] = {0, 0, 0, 0, 0, 0, 0, 0};
    for (int c = 0; c < 128; c++) {
        float wvv = w[c * D4 + tid];
#pragma unroll
        for (int rr = 0; rr < 8; rr++) acc[rr] += x1[rr][c] * wvv;
    }
    float badd = kq ? 0.f : ab1[h * D4 + tid];   // fold b1 into K
    float* outKQ = kq ? Qp : Kp;
#pragma unroll
    for (int rr = 0; rr < 8; rr++)               // pre-scale by log2e
        outKQ[(h * RR + r0 + rr) * D4 + tid] = (acc[rr] + badd) * LOG2E;
    // V projection on kq==0 blocks: 8 rows x 16 s for head h
    if (kq == 0 && tid < 128) {
        int rr = tid >> 4, s = tid & 15;
        const float* wvw = valW + h * CC * SS;
        float a = 0.f;
        for (int k = 0; k < CC; k++) a += x1[rr][64 + k] * wvw[k * SS + s];
        v[(h * RR + r0 + rr) * SS + s] = a;
    }
}

// ============ stage B: attention (4 waves = 4 heads) + proj/FF/LNs ============
// 256 blocks, block = row
__global__ void __launch_bounds__(256) k_stageB(
    const float* __restrict__ Kp, const float* __restrict__ Qp,
    const float* __restrict__ v,
    const float* __restrict__ aw2, const float* __restrict__ ab2,
    float* __restrict__ x,
    const float* __restrict__ projW, const float* __restrict__ projb,
    const float* __restrict__ g2, const float* __restrict__ b2,
    const float* __restrict__ fW1, const float* __restrict__ fb1,
    const float* __restrict__ fW2, const float* __restrict__ fb2,
    const float* __restrict__ g3, const float* __restrict__ b3) {
    int row = blockIdx.x, tid = threadIdx.x;
    int lane = tid & 63, h = tid >> 6;
    int bat = row >> 7, i = row & 127;
    __shared__ __align__(16) float q_s[HH][D4];
    __shared__ __align__(16) float w2_s[HH][D4];
    __shared__ float sc[HH][TT];
    __shared__ float part[HH][4][SS];
    __shared__ float o_s[CC], s_x[CC], s_h[HID_], red[4][CC];
    for (int e = tid; e < HH * D4; e += 256) {
        int hh = e >> 8, d = e & 255;
        q_s[hh][d] = Qp[(hh * RR + row) * D4 + d];
        w2_s[hh][d] = aw2[e] * 0.125f;               // fold C^-0.5
    }
    __syncthreads();
    // scores: lane = j (two j's per lane), d-serial; no cross-lane reduction
    const float* Kb = Kp + (h * RR + bat * TT) * D4;
    float b2s = ab2[h] * 0.125f;
    bool do1 = (lane + 64 <= i);
    const float* kj0 = Kb + lane * D4;
    const float* kj1 = kj0 + 64 * D4;
    float a0 = 0.f, a1 = 0.f;
    for (int d = 0; d < D4; d += 4) {
        float4 q4 = *(const float4*)&q_s[h][d];
        float4 w4 = *(const float4*)&w2_s[h][d];
        if (lane <= i) {
            float4 k0 = *(const float4*)(kj0 + d);
            a0 += sigm2(q4.x + k0.x) * w4.x + sigm2(q4.y + k0.y) * w4.y +
                  sigm2(q4.z + k0.z) * w4.z + sigm2(q4.w + k0.w) * w4.w;
        }
        if (do1) {
            float4 k1 = *(const float4*)(kj1 + d);
            a1 += sigm2(q4.x + k1.x) * w4.x + sigm2(q4.y + k1.y) * w4.y +
                  sigm2(q4.z + k1.z) * w4.z + sigm2(q4.w + k1.w) * w4.w;
        }
    }
    if (lane <= i) sc[h][lane] = a0 + b2s;
    if (do1) sc[h][lane + 64] = a1 + b2s;
    // softmax per head (wave h)
    {
        float s0 = (lane <= i) ? sc[h][lane] : -1e30f;
        float s1 = (lane + 64 <= i) ? sc[h][lane + 64] : -1e30f;
        float m = wred_max(fmaxf(s0, s1));
        float e0 = (lane <= i) ? __expf(s0 - m) : 0.f;
        float e1 = (lane + 64 <= i) ? __expf(s1 - m) : 0.f;
        float inv = __builtin_amdgcn_rcpf(wred_sum(e0 + e1));
        sc[h][lane] = e0 * inv;
        sc[h][lane + 64] = e1 * inv;
    }
    // PV: wave h, 4 j-groups x 16 s
    {
        int jg = lane >> 4, s = lane & 15;
        const float* vb = v + (h * RR + bat * TT) * SS;
        float acc = 0.f;
        for (int j = jg; j <= i; j += 4) acc += sc[h][j] * vb[j * SS + s];
        part[h][jg][s] = acc;
    }
    __syncthreads();
    if (tid < CC) {
        int hh = tid >> 4, s = tid & 15;
        o_s[tid] = part[hh][0][s] + part[hh][1][s] + part[hh][2][s] + part[hh][3][s];
    }
    __syncthreads();
    float xv = 0.f;
    if (tid < CC) {
        float acc = projb[tid];
        for (int k = 0; k < CC; k++) acc += o_s[k] * projW[k * CC + tid];
        xv = x[row * CC + tid] + acc;
        float m = wred_sum(xv) * (1.f / CC);
        float d = xv - m;
        float var = wred_sum(d * d) * (1.f / CC);
        s_x[tid] = d * rsqrtf(var + 1e-5f) * g2[tid] + b2[tid];
    }
    __syncthreads();
    {
        float a = fb1[tid];
        for (int k = 0; k < CC; k++) a += s_x[k] * fW1[k * HID_ + tid];
        s_h[tid] = sigm(a);
    }
    __syncthreads();
    {
        int c = tid & 63, q = tid >> 6;
        float acc = 0.f;
        for (int k = q * 64; k < q * 64 + 64; ++k) acc += s_h[k] * fW2[k * CC + c];
        red[q][c] = acc;
    }
    __syncthreads();
    if (tid < CC) {
        float f = fb2[tid] + red[0][tid] + red[1][tid] + red[2][tid] + red[3][tid];
        float x2 = xv + f;
        float m = wred_sum(x2) * (1.f / CC);
        float d = x2 - m;
        float var = wred_sum(d * d) * (1.f / CC);
        x[row * CC + tid] = d * rsqrtf(var + 1e-5f) * g3[tid] + b3[tid];
    }
}

// ============ lm_head: c-outer register GEMM ============
// grid (125, 4); block = 256 cols x 64 rows; thread = 2 cols x 32 rows
__global__ void __launch_bounds__(256, 4) k_lmhead(const float* __restrict__ x,
                                                   const float* __restrict__ lmW,
                                                   const float* __restrict__ lmb,
                                                   float* __restrict__ out) {
    int tid = threadIdx.x;
    int cp = tid & 127, rg = tid >> 7;
    int v2 = blockIdx.x * 256 + cp * 2;
    int r0 = blockIdx.y * 64;
    int rbase = rg * 32;
    __shared__ float xT[CC][68];            // transposed x tile, padded
    for (int e = tid; e < 64 * CC; e += 256) {
        int r = e >> 6, c = e & 63;
        xT[c][r] = x[(r0 + r) * CC + c];
    }
    __syncthreads();
    float2 bias = *(const float2*)(lmb + v2);
    float2 acc[32];
#pragma unroll
    for (int rr = 0; rr < 32; rr++) acc[rr] = bias;
    for (int c = 0; c < CC; ++c) {
        float2 w = *(const float2*)(lmW + (size_t)c * VV + v2);
#pragma unroll
        for (int q = 0; q < 8; ++q) {
            float4 xr = *(const float4*)&xT[c][rbase + q * 4];
            acc[q * 4 + 0].x += xr.x * w.x; acc[q * 4 + 0].y += xr.x * w.y;
            acc[q * 4 + 1].x += xr.y * w.x; acc[q * 4 + 1].y += xr.y * w.y;
            acc[q * 4 + 2].x += xr.z * w.x; acc[q * 4 + 2].y += xr.z * w.y;
            acc[q * 4 + 3].x += xr.w * w.x; acc[q * 4 + 3].y += xr.w * w.y;
        }
    }
#pragma unroll
    for (int rr = 0; rr < 32; rr++)
        *(float2*)(out + (size_t)(r0 + rbase + rr) * VV + v2) = acc[rr];
}

extern "C" void kernel_launch(void* const* d_in, const int* in_sizes, int n_in,
                              void* d_out, int out_size, void* d_ws, size_t ws_size,
                              hipStream_t stream) {
    const int*   idx   = (const int*)d_in[0];
    const float* tok   = (const float*)d_in[1];
    const float* petab = (const float*)d_in[2];
    const float* peW1  = (const float*)d_in[3];
    const float* peb1  = (const float*)d_in[4];
    const float* peW2  = (const float*)d_in[5];
    const float* peb2  = (const float*)d_in[6];
    const float* peg   = (const float*)d_in[7];
    const float* pebb  = (const float*)d_in[8];
    const float* ln1g  = (const float*)d_in[9];
    const float* ln1b  = (const float*)d_in[10];
    const float* attW1 = (const float*)d_in[11];
    const float* attb1 = (const float*)d_in[12];
    const float* attW2 = (const float*)d_in[13];
    const float* attb2 = (const float*)d_in[14];
    const float* valW  = (const float*)d_in[15];
    const float* projW = (const float*)d_in[16];
    const float* projb = (const float*)d_in[17];
    const float* ln2g  = (const float*)d_in[18];
    const float* ln2b  = (const float*)d_in[19];
    const float* ffW1  = (const float*)d_in[20];
    const float* ffb1  = (const float*)d_in[21];
    const float* ffW2  = (const float*)d_in[22];
    const float* ffb2  = (const float*)d_in[23];
    const float* ln3g  = (const float*)d_in[24];
    const float* ln3b  = (const float*)d_in[25];
    const float* lmW   = (const float*)d_in[26];
    const float* lmb   = (const float*)d_in[27];

    float* ws  = (float*)d_ws;
    float* x   = ws;                  // 16384
    float* pos = ws + 16384;          // 32768
    float* v   = ws + 49152;          // 16384
    float* Kp  = ws + 65536;          // 262144 (pre-scaled, +b1)
    float* Qp  = ws + 327680;         // 262144 (pre-scaled)

    k_embed_pos<<<768, CC, 0, stream>>>(idx, tok, petab, peW1, peb1, peW2, peb2,
                                        peg, pebb, x, pos);
    for (int p = 0; p < NPE_; p++) {
        k_stageA<<<256, 256, 0, stream>>>(x, pos + p * TT * CC, ln1g, ln1b,
                                          attW1, attb1, valW, Kp, Qp, v);
        k_stageB<<<256, 256, 0, stream>>>(Kp, Qp, v, attW2, attb2, x,
                                          projW, projb, ln2g, ln2b, ffW1, ffb1,
                                          ffW2, ffb2, ln3g, ln3b);
    }
    k_lmhead<<<dim3(125, 4), 256, 0, stream>>>(x, lmW, lmb, (float*)d_out);
}

// Round 8
// 180.531 us; speedup vs baseline: 4.3294x; 1.4259x over previous
//
#include <hip/hip_runtime.h>

// Model dims (fixed by the problem)
#define TT    128
#define CC    64
#define HH    4
#define SS    16
#define D4    256     // 4*C
#define HID_  256
#define VV    32000
#define NPE_  4
#define RR    256     // B*T
#define LOG2E 1.44269504f

__device__ __forceinline__ float wred_sum(float v) {
#pragma unroll
    for (int off = 32; off; off >>= 1) v += __shfl_xor(v, off, 64);
    return v;
}
__device__ __forceinline__ float wred_max(float v) {
#pragma unroll
    for (int off = 32; off; off >>= 1) v = fmaxf(v, __shfl_xor(v, off, 64));
    return v;
}
__device__ __forceinline__ float sigm(float x) {
    return __builtin_amdgcn_rcpf(1.f + exp2f(-x * LOG2E));
}
__device__ __forceinline__ float sigm2(float t) {   // input pre-scaled by log2e
    return __builtin_amdgcn_rcpf(1.f + exp2f(-t));
}

// ============ embed + all positional embeddings (one launch) ============
// blocks 0..511: pos (p = blk>>7, t = blk&127); blocks 512..767: embed rows
__global__ void k_embed_pos(const int* __restrict__ idx, const float* __restrict__ tok,
                            const float* __restrict__ pe_tab, const float* __restrict__ W1,
                            const float* __restrict__ b1, const float* __restrict__ W2,
                            const float* __restrict__ b2, const float* __restrict__ g,
                            const float* __restrict__ bb,
                            float* __restrict__ x, float* __restrict__ pos) {
    int blk = blockIdx.x, c = threadIdx.x;
    if (blk >= 512) {
        int r = blk - 512;
        x[r * CC + c] = tok[idx[r] * CC + c];
        return;
    }
    int p = blk >> 7, t = blk & 127;
    __shared__ float s_pe[CC], s_h[CC];
    s_pe[c] = pe_tab[(p * TT + t) * CC + c];
    __syncthreads();
    const float* w1 = W1 + p * CC * CC;
    float a = b1[p * CC + c];
    for (int k = 0; k < CC; k++) a += s_pe[k] * w1[k * CC + c];
    s_h[c] = sigm(a);
    __syncthreads();
    const float* w2 = W2 + p * CC * CC;
    float o = b2[p * CC + c];
    for (int k = 0; k < CC; k++) o += s_h[k] * w2[k * CC + c];
    float m = wred_sum(o) * (1.f / CC);
    float d = o - m;
    float var = wred_sum(d * d) * (1.f / CC);
    pos[(p * TT + t) * CC + c] =
        d * rsqrtf(var + 1e-5f) * g[p * CC + c] + bb[p * CC + c];
}

// ============ stage A: LN1 + K/Q proj (+V on kq==0 blocks) ============
// 256 blocks: rg = blk&31 (8 rows), kq = (blk>>5)&1, h = blk>>6
__global__ void __launch_bounds__(256) k_stageA(
    const float* __restrict__ x, const float* __restrict__ pos_p,
    const float* __restrict__ ln1g, const float* __restrict__ ln1b,
    const float* __restrict__ attW1, const float* __restrict__ ab1,
    const float* __restrict__ valW,
    float* __restrict__ Kp, float* __restrict__ Qp, float* __restrict__ v) {
    int blk = blockIdx.x, tid = threadIdx.x;
    int lane = tid & 63, wv = tid >> 6;
    int rg = blk & 31, kq = (blk >> 5) & 1, h = blk >> 6;
    int r0 = rg * 8;
    __shared__ float x1[8][128];
#pragma unroll
    for (int pass = 0; pass < 2; ++pass) {
        int rr = wv + pass * 4;
        float xv = x[(r0 + rr) * CC + lane];
        float m = wred_sum(xv) * (1.f / CC);
        float d = xv - m;
        float var = wred_sum(d * d) * (1.f / CC);
        x1[rr][64 + lane] = d * rsqrtf(var + 1e-5f) * ln1g[lane] + ln1b[lane];
    }
    for (int e = tid; e < 512; e += 256) {
        int rr = e >> 6, cc = e & 63;
        int t = (r0 + rr) & (TT - 1);
        x1[rr][cc] = pos_p[t * CC + cc];
    }
    __syncthreads();
    const float* w = attW1 + (h * D4 + kq * 128) * D4;
    float acc[8] = {0, 0, 0, 0, 0, 0, 0, 0};
    for (int c = 0; c < 128; c++) {
        float wvv = w[c * D4 + tid];
#pragma unroll
        for (int rr = 0; rr < 8; rr++) acc[rr] += x1[rr][c] * wvv;
    }
    float badd = kq ? 0.f : ab1[h * D4 + tid];   // fold b1 into K
    float* outKQ = kq ? Qp : Kp;
#pragma unroll
    for (int rr = 0; rr < 8; rr++)               // pre-scale by log2e
        outKQ[(h * RR + r0 + rr) * D4 + tid] = (acc[rr] + badd) * LOG2E;
    // V projection on kq==0 blocks: 8 rows x 16 s for head h
    if (kq == 0 && tid < 128) {
        int rr = tid >> 4, s = tid & 15;
        const float* wvw = valW + h * CC * SS;
        float a = 0.f;
        for (int k = 0; k < CC; k++) a += x1[rr][64 + k] * wvw[k * SS + s];
        v[(h * RR + r0 + rr) * SS + s] = a;
    }
}

// ============ stage B: attention + proj/FF/LNs, 1024 thr/block ============
// 256 blocks = rows; 16 waves = 4 heads x 4 j-groups; lane = d (coalesced K)
__global__ void __launch_bounds__(1024, 1) k_stageB(
    const float* __restrict__ Kp, const float* __restrict__ Qp,
    const float* __restrict__ v,
    const float* __restrict__ aw2, const float* __restrict__ ab2,
    float* __restrict__ x,
    const float* __restrict__ projW, const float* __restrict__ projb,
    const float* __restrict__ g2, const float* __restrict__ b2,
    const float* __restrict__ fW1, const float* __restrict__ fb1,
    const float* __restrict__ fW2, const float* __restrict__ fb2,
    const float* __restrict__ g3, const float* __restrict__ b3) {
    int row = blockIdx.x, tid = threadIdx.x;
    int lane = tid & 63, wv = tid >> 6;
    int h = wv & 3, jg = wv >> 2;
    int bat = row >> 7, i = row & 127;
    __shared__ __align__(16) float q_s[HH][D4];
    __shared__ __align__(16) float w2_s[HH][D4];
    __shared__ float sc[HH][TT];
    __shared__ float part[HH][16][17];
    __shared__ float o_s[CC], s_x[CC], s_h[HID_], red[4][CC];
    for (int e = tid; e < HH * D4; e += 1024) {
        q_s[e >> 8][e & 255] = Qp[((e >> 8) * RR + row) * D4 + (e & 255)];
        w2_s[e >> 8][e & 255] = aw2[e] * 0.125f;     // fold C^-0.5
    }
    __syncthreads();
    // scores: wave (h, jg) handles j = jg, jg+4, ...; lane = d (coalesced)
    {
        float4 qq = *(const float4*)&q_s[h][lane * 4];
        float4 ww = *(const float4*)&w2_s[h][lane * 4];
        float b2s = ab2[h] * 0.125f;
        const float* Kb = Kp + (h * RR + bat * TT) * D4;
        for (int j = jg; j <= i; j += 4) {
            float4 kk = *(const float4*)(Kb + j * D4 + lane * 4);
            float a = sigm2(qq.x + kk.x) * ww.x + sigm2(qq.y + kk.y) * ww.y +
                      sigm2(qq.z + kk.z) * ww.z + sigm2(qq.w + kk.w) * ww.w;
            a = wred_sum(a);
            if (lane == 0) sc[h][j] = a + b2s;
        }
    }
    __syncthreads();
    // softmax: waves 0..3, wave hh = head hh
    if (wv < 4) {
        int hh = wv;
        float s0 = (lane <= i) ? sc[hh][lane] : -1e30f;
        float s1 = (lane + 64 <= i) ? sc[hh][lane + 64] : -1e30f;
        float m = wred_max(fmaxf(s0, s1));
        float e0 = (lane <= i) ? __expf(s0 - m) : 0.f;
        float e1 = (lane + 64 <= i) ? __expf(s1 - m) : 0.f;
        float inv = __builtin_amdgcn_rcpf(wred_sum(e0 + e1));
        sc[hh][lane] = e0 * inv;
        sc[hh][lane + 64] = e1 * inv;
    }
    __syncthreads();
    // PV: all 16 waves; wave (h,jg), lane -> (jo, s): 16 j-offsets x 16 s
    {
        int jo = lane >> 4, s = lane & 15;
        int jstart = jg * 4 + jo;
        const float* vb = v + (h * RR + bat * TT) * SS;
        float acc = 0.f;
        for (int j = jstart; j <= i; j += 16) acc += sc[h][j] * vb[j * SS + s];
        part[h][jstart][s] = acc;
    }
    __syncthreads();
    if (tid < CC) {
        int hh = tid >> 4, s = tid & 15;
        float a = 0.f;
#pragma unroll
        for (int k = 0; k < 16; ++k) a += part[hh][k][s];
        o_s[tid] = a;
    }
    __syncthreads();
    // post: proj + residual + LN2 (wave 0)
    float xv = 0.f;
    if (tid < CC) {
        float acc = projb[tid];
        for (int k = 0; k < CC; k++) acc += o_s[k] * projW[k * CC + tid];
        xv = x[row * CC + tid] + acc;
        float m = wred_sum(xv) * (1.f / CC);
        float d = xv - m;
        float var = wred_sum(d * d) * (1.f / CC);
        s_x[tid] = d * rsqrtf(var + 1e-5f) * g2[tid] + b2[tid];
    }
    __syncthreads();
    if (tid < 256) {
        float a = fb1[tid];
        for (int k = 0; k < CC; k++) a += s_x[k] * fW1[k * HID_ + tid];
        s_h[tid] = sigm(a);
    }
    __syncthreads();
    if (tid < 256) {
        int c = tid & 63, q = tid >> 6;
        float acc = 0.f;
        for (int k = q * 64; k < q * 64 + 64; ++k) acc += s_h[k] * fW2[k * CC + c];
        red[q][c] = acc;
    }
    __syncthreads();
    if (tid < CC) {
        float f = fb2[tid] + red[0][tid] + red[1][tid] + red[2][tid] + red[3][tid];
        float x2 = xv + f;
        float m = wred_sum(x2) * (1.f / CC);
        float d = x2 - m;
        float var = wred_sum(d * d) * (1.f / CC);
        x[row * CC + tid] = d * rsqrtf(var + 1e-5f) * g3[tid] + b3[tid];
    }
}

// ============ lm_head: c-outer register GEMM ============
// grid (125, 4); block = 256 cols x 64 rows; thread = 2 cols x 32 rows
__global__ void __launch_bounds__(256, 4) k_lmhead(const float* __restrict__ x,
                                                   const float* __restrict__ lmW,
                                                   const float* __restrict__ lmb,
                                                   float* __restrict__ out) {
    int tid = threadIdx.x;
    int cp = tid & 127, rg = tid >> 7;
    int v2 = blockIdx.x * 256 + cp * 2;
    int r0 = blockIdx.y * 64;
    int rbase = rg * 32;
    __shared__ float xT[CC][68];            // transposed x tile, padded
    for (int e = tid; e < 64 * CC; e += 256) {
        int r = e >> 6, c = e & 63;
        xT[c][r] = x[(r0 + r) * CC + c];
    }
    __syncthreads();
    float2 bias = *(const float2*)(lmb + v2);
    float2 acc[32];
#pragma unroll
    for (int rr = 0; rr < 32; rr++) acc[rr] = bias;
    for (int c = 0; c < CC; ++c) {
        float2 w = *(const float2*)(lmW + (size_t)c * VV + v2);
#pragma unroll
        for (int q = 0; q < 8; ++q) {
            float4 xr = *(const float4*)&xT[c][rbase + q * 4];
            acc[q * 4 + 0].x += xr.x * w.x; acc[q * 4 + 0].y += xr.x * w.y;
            acc[q * 4 + 1].x += xr.y * w.x; acc[q * 4 + 1].y += xr.y * w.y;
            acc[q * 4 + 2].x += xr.z * w.x; acc[q * 4 + 2].y += xr.z * w.y;
            acc[q * 4 + 3].x += xr.w * w.x; acc[q * 4 + 3].y += xr.w * w.y;
        }
    }
#pragma unroll
    for (int rr = 0; rr < 32; rr++)
        *(float2*)(out + (size_t)(r0 + rbase + rr) * VV + v2) = acc[rr];
}

extern "C" void kernel_launch(void* const* d_in, const int* in_sizes, int n_in,
                              void* d_out, int out_size, void* d_ws, size_t ws_size,
                              hipStream_t stream) {
    const int*   idx   = (const int*)d_in[0];
    const float* tok   = (const float*)d_in[1];
    const float* petab = (const float*)d_in[2];
    const float* peW1  = (const float*)d_in[3];
    const float* peb1  = (const float*)d_in[4];
    const float* peW2  = (const float*)d_in[5];
    const float* peb2  = (const float*)d_in[6];
    const float* peg   = (const float*)d_in[7];
    const float* pebb  = (const float*)d_in[8];
    const float* ln1g  = (const float*)d_in[9];
    const float* ln1b  = (const float*)d_in[10];
    const float* attW1 = (const float*)d_in[11];
    const float* attb1 = (const float*)d_in[12];
    const float* attW2 = (const float*)d_in[13];
    const float* attb2 = (const float*)d_in[14];
    const float* valW  = (const float*)d_in[15];
    const float* projW = (const float*)d_in[16];
    const float* projb = (const float*)d_in[17];
    const float* ln2g  = (const float*)d_in[18];
    const float* ln2b  = (const float*)d_in[19];
    const float* ffW1  = (const float*)d_in[20];
    const float* ffb1  = (const float*)d_in[21];
    const float* ffW2  = (const float*)d_in[22];
    const float* ffb2  = (const float*)d_in[23];
    const float* ln3g  = (const float*)d_in[24];
    const float* ln3b  = (const float*)d_in[25];
    const float* lmW   = (const float*)d_in[26];
    const float* lmb   = (const float*)d_in[27];

    float* ws  = (float*)d_ws;
    float* x   = ws;                  // 16384
    float* pos = ws + 16384;          // 32768
    float* v   = ws + 49152;          // 16384
    float* Kp  = ws + 65536;          // 262144 (pre-scaled, +b1)
    float* Qp  = ws + 327680;         // 262144 (pre-scaled)

    k_embed_pos<<<768, CC, 0, stream>>>(idx, tok, petab, peW1, peb1, peW2, peb2,
                                        peg, pebb, x, pos);
    for (int p = 0; p < NPE_; p++) {
        k_stageA<<<256, 256, 0, stream>>>(x, pos + p * TT * CC, ln1g, ln1b,
                                          attW1, attb1, valW, Kp, Qp, v);
        k_stageB<<<256, 1024, 0, stream>>>(Kp, Qp, v, attW2, attb2, x,
                                           projW, projb, ln2g, ln2b, ffW1, ffb1,
                                           ffW2, ffb2, ln3g, ln3b);
    }
    k_lmhead<<<dim3(125, 4), 256, 0, stream>>>(x, lmW, lmb, (float*)d_out);
}